// Round 1
// baseline (66.606 us; speedup 1.0000x reference)
//
#include <hip/hip_runtime.h>

__device__ __forceinline__ float4 f4add(float4 a, float4 b) {
    return make_float4(a.x + b.x, a.y + b.y, a.z + b.z, a.w + b.w);
}
__device__ __forceinline__ float4 f4sub(float4 a, float4 b) {
    return make_float4(a.x - b.x, a.y - b.y, a.z - b.z, a.w - b.w);
}
__device__ __forceinline__ float4 f4scale(float4 a, float s) {
    return make_float4(a.x * s, a.y * s, a.z * s, a.w * s);
}

// Single-level batched 3D inverse Haar.
// coeffs: (B, 8, D, D, D), subband s = 4*b0 + 2*b1 + b2 (b0->D axis, b1->H, b2->W)
// approx: (B, D, D, D) replaces subband 0 when HAS_APPROX
// out:    (B, 2D, 2D, 2D)
// Each thread: one (b,d,h) row segment of 4 consecutive w -> 4x4x4... no:
// reads 8 subbands x float4 (128 B), writes 2x2 rows x 8 consecutive floats (128 B).
template <int D, bool HAS_APPROX>
__global__ __launch_bounds__(256) void idwt3d_kernel(
    const float* __restrict__ coeffs, const float* __restrict__ approx,
    float* __restrict__ out, int B) {
    constexpr int H = D, W = D;
    constexpr int W4 = W / 4;
    const int idx = blockIdx.x * 256 + threadIdx.x;
    const int total = B * D * H * W4;
    if (idx >= total) return;

    const int w4 = idx % W4;
    int t = idx / W4;
    const int h = t % H;
    t /= H;
    const int d = t % D;
    const int b = t / D;

    const size_t plane = (size_t)D * H * W;
    const size_t voxoff = ((size_t)d * H + h) * W + (size_t)w4 * 4;

    float4 c[8];
#pragma unroll
    for (int s = 0; s < 8; ++s) {
        if (HAS_APPROX && s == 0) {
            c[0] = *reinterpret_cast<const float4*>(approx + (size_t)b * plane + voxoff);
        } else {
            c[s] = *reinterpret_cast<const float4*>(coeffs + ((size_t)b * 8 + s) * plane + voxoff);
        }
    }

    // Stage W (bit b2): e = even-k, o = odd-k; m = 2*b0 + b1
    float4 e[4], o[4];
#pragma unroll
    for (int m = 0; m < 4; ++m) {
        e[m] = f4add(c[2 * m], c[2 * m + 1]);
        o[m] = f4sub(c[2 * m], c[2 * m + 1]);
    }
    // Stage H (bit b1): [k-parity][j-parity][b0]
    float4 ke_je[2], ke_jo[2], ko_je[2], ko_jo[2];
#pragma unroll
    for (int b0 = 0; b0 < 2; ++b0) {
        ke_je[b0] = f4add(e[2 * b0], e[2 * b0 + 1]);
        ke_jo[b0] = f4sub(e[2 * b0], e[2 * b0 + 1]);
        ko_je[b0] = f4add(o[2 * b0], o[2 * b0 + 1]);
        ko_jo[b0] = f4sub(o[2 * b0], o[2 * b0 + 1]);
    }

    const float SC = 0.35355339059327373f;  // 2^{-3/2}
    const size_t ob = (size_t)b * (2 * D);

#pragma unroll
    for (int i = 0; i < 2; ++i) {
#pragma unroll
        for (int j = 0; j < 2; ++j) {
            float4 ve, vo;  // final even-k / odd-k values for row (2d+i, 2h+j)
            const float4* keP = (j == 0) ? ke_je : ke_jo;
            const float4* koP = (j == 0) ? ko_je : ko_jo;
            if (i == 0) {
                ve = f4add(keP[0], keP[1]);
                vo = f4add(koP[0], koP[1]);
            } else {
                ve = f4sub(keP[0], keP[1]);
                vo = f4sub(koP[0], koP[1]);
            }
            ve = f4scale(ve, SC);
            vo = f4scale(vo, SC);
            const float4 lo = make_float4(ve.x, vo.x, ve.y, vo.y);
            const float4 hi = make_float4(ve.z, vo.z, ve.w, vo.w);
            const size_t row =
                ((ob + (size_t)(2 * d + i)) * (2 * H) + (size_t)(2 * h + j)) * (2 * W);
            float4* op = reinterpret_cast<float4*>(out + row + (size_t)w4 * 8);
            op[0] = lo;
            op[1] = hi;
        }
    }
}

extern "C" void kernel_launch(void* const* d_in, const int* in_sizes, int n_in,
                              void* d_out, int out_size, void* d_ws, size_t ws_size,
                              hipStream_t stream) {
    const float* scale0 = (const float*)d_in[0];  // (B,8,64,64,64)
    const float* scale1 = (const float*)d_in[1];  // (B,8,32,32,32)
    const float* scale2 = (const float*)d_in[2];  // (B,8,16,16,16)
    float* out = (float*)d_out;                   // (B,1,128,128,128)

    const int B = in_sizes[0] / (8 * 64 * 64 * 64);  // 16

    float* approx2 = (float*)d_ws;                          // (B,32,32,32): 2 MiB
    float* approx1 = approx2 + (size_t)B * 32 * 32 * 32;    // (B,64,64,64): 16.8 MB

    // Level 2 (coarsest): scale2 -> approx2 (B,32,32,32)
    {
        const int total = B * 16 * 16 * (16 / 4);
        idwt3d_kernel<16, false><<<(total + 255) / 256, 256, 0, stream>>>(
            scale2, nullptr, approx2, B);
    }
    // Level 1: scale1 (aaa <- approx2) -> approx1 (B,64,64,64)
    {
        const int total = B * 32 * 32 * (32 / 4);
        idwt3d_kernel<32, true><<<(total + 255) / 256, 256, 0, stream>>>(
            scale1, approx2, approx1, B);
    }
    // Level 0: scale0 (aaa <- approx1) -> out (B,128,128,128)
    {
        const int total = B * 64 * 64 * (64 / 4);
        idwt3d_kernel<64, true><<<(total + 255) / 256, 256, 0, stream>>>(
            scale0, approx1, out, B);
    }
}

// Round 3
// 54.025 us; speedup vs baseline: 1.2329x; 1.2329x over previous
//
#include <hip/hip_runtime.h>

typedef float fvec2 __attribute__((ext_vector_type(2)));
typedef float fvec4 __attribute__((ext_vector_type(4)));

// Fully fused 3-level inverse 3D Haar DWT.
// out(B,128,128,128) from scale0(B,8,64^3), scale1(B,8,32^3), scale2(B,8,16^3).
// Subband s = 4*b0 + 2*b1 + b2 (b0 -> D axis, b1 -> H, b2 -> W); each inverse
// level: out(2d+io,2h+jo,2w+ko) = 2^{-3/2} * sum_s c_s * (-1)^(io*b0+jo*b1+ko*b2).
//
// One thread per level-1 voxel (b,d1,h1,w1):
//   1. approx2 value (single element) from 8 scale2 coeffs (partial butterfly)
//   2. level-1 butterfly -> 8 approx1 values (the 2x2x2 block)
//   3. 8 level-0 butterflies (detail subbands from scale0) -> 4x4x4 output tile

__global__ __launch_bounds__(256) void idwt3_fused_kernel(
    const float* __restrict__ scale0, const float* __restrict__ scale1,
    const float* __restrict__ scale2, float* __restrict__ out, int B) {
    constexpr float SC = 0.35355339059327373f;  // 2^{-3/2}

    const int idx = blockIdx.x * 256 + threadIdx.x;
    const int w1 = idx & 31;
    const int h1 = (idx >> 5) & 31;
    const int d1 = (idx >> 10) & 31;
    const int b = idx >> 15;
    if (b >= B) return;

    // ---- level 2: one approx2 value at (d1,h1,w1) ----
    const int d2 = d1 >> 1, h2 = h1 >> 1, w2 = w1 >> 1;
    const int i2 = d1 & 1, j2 = h1 & 1, k2 = w1 & 1;
    constexpr size_t p2 = 16 * 16 * 16;
    const float* s2 = scale2 + (size_t)b * 8 * p2 + ((size_t)d2 * 16 + h2) * 16 + w2;
    float c2[8];
#pragma unroll
    for (int s = 0; s < 8; ++s) c2[s] = s2[s * p2];
    const float x0 = k2 ? (c2[0] - c2[1]) : (c2[0] + c2[1]);
    const float x1 = k2 ? (c2[2] - c2[3]) : (c2[2] + c2[3]);
    const float x2 = k2 ? (c2[4] - c2[5]) : (c2[4] + c2[5]);
    const float x3 = k2 ? (c2[6] - c2[7]) : (c2[6] + c2[7]);
    const float y0 = j2 ? (x0 - x1) : (x0 + x1);
    const float y1 = j2 ? (x2 - x3) : (x2 + x3);
    const float a2 = SC * (i2 ? (y0 - y1) : (y0 + y1));

    // ---- level 1: full butterfly -> a1[i][j][k] ----
    constexpr size_t p1 = 32 * 32 * 32;
    const float* s1 = scale1 + (size_t)b * 8 * p1 + ((size_t)d1 * 32 + h1) * 32 + w1;
    float c1[8];
    c1[0] = a2;
#pragma unroll
    for (int s = 1; s < 8; ++s) c1[s] = __builtin_nontemporal_load(s1 + s * p1);
    const float e0 = c1[0] + c1[1], q0 = c1[0] - c1[1];
    const float e1 = c1[2] + c1[3], q1 = c1[2] - c1[3];
    const float e2 = c1[4] + c1[5], q2 = c1[4] - c1[5];
    const float e3 = c1[6] + c1[7], q3 = c1[6] - c1[7];
    const float ee0 = e0 + e1, eo0 = e0 - e1;  // b0=0: jo=0 / jo=1 (ko=0)
    const float ee1 = e2 + e3, eo1 = e2 - e3;  // b0=1
    const float oe0 = q0 + q1, oo0 = q0 - q1;  // ko=1
    const float oe1 = q2 + q3, oo1 = q2 - q3;
    float a1[2][2][2];  // [i][j][k]
    a1[0][0][0] = SC * (ee0 + ee1);
    a1[1][0][0] = SC * (ee0 - ee1);
    a1[0][1][0] = SC * (eo0 + eo1);
    a1[1][1][0] = SC * (eo0 - eo1);
    a1[0][0][1] = SC * (oe0 + oe1);
    a1[1][0][1] = SC * (oe0 - oe1);
    a1[0][1][1] = SC * (oo0 + oo1);
    a1[1][1][1] = SC * (oo0 - oo1);

    // ---- level 0: 8 butterflies -> 4x4x4 output tile ----
    constexpr size_t p0 = 64 * 64 * 64;
    const float* s0b = scale0 + (size_t)b * 8 * p0;
    float* ob = out + (size_t)b * 128 * 128 * 128;

#pragma unroll
    for (int i = 0; i < 2; ++i) {
#pragma unroll
        for (int j = 0; j < 2; ++j) {
            const int d0 = 2 * d1 + i, h0 = 2 * h1 + j;
            const size_t voff = ((size_t)d0 * 64 + h0) * 64 + 2 * w1;
            fvec2 det[8];  // s=1..7, [0] -> k=0, [1] -> k=1
#pragma unroll
            for (int s = 1; s < 8; ++s)
                det[s] = __builtin_nontemporal_load(
                    reinterpret_cast<const fvec2*>(s0b + s * p0 + voff));

            float o[2][2][2][2];  // [k][io][jo][ko]
#pragma unroll
            for (int k = 0; k < 2; ++k) {
                const float g0 = det[1][k];
                const float g1 = det[2][k];
                const float g2 = det[3][k];
                const float g3 = det[4][k];
                const float g4 = det[5][k];
                const float g5 = det[6][k];
                const float g6 = det[7][k];
                const float ca = a1[i][j][k];
                const float fe0 = ca + g0, fq0 = ca - g0;
                const float fe1 = g1 + g2, fq1 = g1 - g2;
                const float fe2 = g3 + g4, fq2 = g3 - g4;
                const float fe3 = g5 + g6, fq3 = g5 - g6;
                const float fee0 = fe0 + fe1, feo0 = fe0 - fe1;
                const float fee1 = fe2 + fe3, feo1 = fe2 - fe3;
                const float foe0 = fq0 + fq1, foo0 = fq0 - fq1;
                const float foe1 = fq2 + fq3, foo1 = fq2 - fq3;
                o[k][0][0][0] = SC * (fee0 + fee1);
                o[k][1][0][0] = SC * (fee0 - fee1);
                o[k][0][1][0] = SC * (feo0 + feo1);
                o[k][1][1][0] = SC * (feo0 - feo1);
                o[k][0][0][1] = SC * (foe0 + foe1);
                o[k][1][0][1] = SC * (foe0 - foe1);
                o[k][0][1][1] = SC * (foo0 + foo1);
                o[k][1][1][1] = SC * (foo0 - foo1);
            }
            // rows (4d1+2i+io, 4h1+2j+jo), w = [4*w1, 4*w1+4)
#pragma unroll
            for (int io = 0; io < 2; ++io) {
#pragma unroll
                for (int jo = 0; jo < 2; ++jo) {
                    fvec4 v;
                    v[0] = o[0][io][jo][0];
                    v[1] = o[0][io][jo][1];
                    v[2] = o[1][io][jo][0];
                    v[3] = o[1][io][jo][1];
                    float* p = ob + ((size_t)(4 * d1 + 2 * i + io) * 128 +
                                     (size_t)(4 * h1 + 2 * j + jo)) * 128 +
                               4 * w1;
                    __builtin_nontemporal_store(v, reinterpret_cast<fvec4*>(p));
                }
            }
        }
    }
}

extern "C" void kernel_launch(void* const* d_in, const int* in_sizes, int n_in,
                              void* d_out, int out_size, void* d_ws, size_t ws_size,
                              hipStream_t stream) {
    const float* scale0 = (const float*)d_in[0];  // (B,8,64,64,64)
    const float* scale1 = (const float*)d_in[1];  // (B,8,32,32,32)
    const float* scale2 = (const float*)d_in[2];  // (B,8,16,16,16)
    float* out = (float*)d_out;                   // (B,1,128,128,128)

    const int B = in_sizes[0] / (8 * 64 * 64 * 64);  // 16
    const int total = B * 32 * 32 * 32;              // one thread per level-1 voxel
    idwt3_fused_kernel<<<(total + 255) / 256, 256, 0, stream>>>(scale0, scale1,
                                                                scale2, out, B);
}